// Round 3
// baseline (271.288 us; speedup 1.0000x reference)
//
#include <hip/hip_runtime.h>

#define NAGENTS 8
#define MITEMS 16
#define NM 128          // NAGENTS*MITEMS
#define MENU 256
#define SFULL 257       // MENU + null entry

__device__ __forceinline__ float wredmax(float v) {
#pragma unroll
    for (int o = 32; o; o >>= 1) v = fmaxf(v, __shfl_xor(v, o));
    return v;
}
__device__ __forceinline__ float wredsum(float v) {
#pragma unroll
    for (int o = 32; o; o >>= 1) v += __shfl_xor(v, o);
    return v;
}

// 512 threads/block, one block per auction. ALL 256 menu rows live in
// registers (Pf[4][16] = 64 VGPR/thread: 4 rows x 16-float agent slice).
// No LDS payload, and ALL global stores are deferred past the last barrier
// so no __syncthreads ever drains a store-ack. LDS ~15.5KB; 2 blocks/CU
// (VGPR-bound at <=128 via launch_bounds).
__global__ __launch_bounds__(512, 4) void cama_kernel(
    const float* __restrict__ bids,   // B,8,16
    const float* __restrict__ allocs, // B,256,8,16
    const float* __restrict__ wvec,   // B,8
    const float* __restrict__ bvec,   // B,256
    const float* __restrict__ tempp,  // 1
    float* __restrict__ out, int Bsz)
{
    __shared__ float lds_pwT[NAGENTS * MENU];   // 8KB, swizzled [n][s^(n<<2)]
    __shared__ float lds_tot[MENU];
    __shared__ float lds_bb[MENU];
    __shared__ float lds_ch[SFULL];
    __shared__ float lds_scr[8 * NM];           // 4KB item scratch
    __shared__ float lds_rcs[NAGENTS], lds_rb[NAGENTS], lds_cw[NAGENTS];
    __shared__ float lds_ab;

    const int u = threadIdx.x;       // 0..511
    const int lane = u & 63;
    const int wave = u >> 6;         // 0..7
    const int n = u & 7;             // agent slice owned by this thread
    const int sg = u >> 3;           // 0..63 (s-group)
    const int b = blockIdx.x;
    const size_t bb = (size_t)b;

    float* out_choice = out;                                  // B*257
    float* out_item   = out + (size_t)Bsz * SFULL;            // B*128
    float* out_pay    = out_item + (size_t)Bsz * NM;          // 8*B
    float* out_all    = out_pay + (size_t)NAGENTS * Bsz;      // B*257*128

    // stage b-vector (consumed after barrier 1); q/w read directly (L1 broadcast)
    if (u < MENU) lds_bb[u] = bvec[bb * MENU + u];

    const float temp = tempp[0];
    const float w_n = wvec[bb * NAGENTS + n];
    float qf[16];
    {
        const float4* bq = (const float4*)(bids + bb * NM) + (n << 2);
        float4 qa = bq[0], qb = bq[1], qc = bq[2], qd = bq[3];
        qf[0]=qa.x; qf[1]=qa.y; qf[2]=qa.z; qf[3]=qa.w;
        qf[4]=qb.x; qf[5]=qb.y; qf[6]=qb.z; qf[7]=qb.w;
        qf[8]=qc.x; qf[9]=qc.y; qf[10]=qc.z; qf[11]=qc.w;
        qf[12]=qd.x; qf[13]=qd.y; qf[14]=qd.z; qf[15]=qd.w;
    }

    float Pf[4][16];   // payload: rows s = c*64+sg, agent-n 16-float slice

    // Phase 1: stream allocs -> regs, welfare into LDS. No stores here.
#pragma unroll
    for (int c = 0; c < 4; ++c) {
        const int s = (c << 6) + sg;
        const float4* src = (const float4*)(allocs + ((bb << 8) + s) * NM) + (n << 2);
        float4 a0 = src[0], a1 = src[1], a2 = src[2], a3 = src[3];
        Pf[c][0]=a0.x;  Pf[c][1]=a0.y;  Pf[c][2]=a0.z;  Pf[c][3]=a0.w;
        Pf[c][4]=a1.x;  Pf[c][5]=a1.y;  Pf[c][6]=a1.z;  Pf[c][7]=a1.w;
        Pf[c][8]=a2.x;  Pf[c][9]=a2.y;  Pf[c][10]=a2.z; Pf[c][11]=a2.w;
        Pf[c][12]=a3.x; Pf[c][13]=a3.y; Pf[c][14]=a3.z; Pf[c][15]=a3.w;
        float util = 0.f;
#pragma unroll
        for (int k = 0; k < 16; ++k) util += Pf[c][k] * qf[k];
        float pwv = w_n * util;
        lds_pwT[(n << 8) + (s ^ (n << 2))] = pwv;
        float t4 = pwv;
        t4 += __shfl_xor(t4, 1);
        t4 += __shfl_xor(t4, 2);
        t4 += __shfl_xor(t4, 4);
        if (n == 0) lds_tot[s] = t4;
    }
    __syncthreads();   // b1: pwT/tot/bb ready (drains only loads + LDS)

    // Round A: full softmax (wave 0) + 8 leave-one-out softmaxes (wave i -> agent i)
    if (wave == 0) {
        float xs[4], bl[4], es[4];
        float mx = -1e30f;
#pragma unroll
        for (int c = 0; c < 4; ++c) {
            int v = (c << 6) | lane;
            bl[c] = lds_bb[v];
            float x = (lds_tot[v] + bl[c]) * temp;
            xs[c] = x; mx = fmaxf(mx, x);
        }
        mx = fmaxf(wredmax(mx), 0.f);   // null entry has x=0
        float se = 0.f, sab = 0.f;
#pragma unroll
        for (int c = 0; c < 4; ++c) { es[c] = __expf(xs[c] - mx); se += es[c]; sab += es[c] * bl[c]; }
        float en = __expf(-mx);
        se = wredsum(se) + en;
        sab = wredsum(sab);
        float inv = 1.f / se;
#pragma unroll
        for (int c = 0; c < 4; ++c) lds_ch[(c << 6) | lane] = es[c] * inv;
        if (lane == 0) {
            lds_ch[MENU] = en * inv;
            lds_ab = sab * inv;
        }
    }
    {
        const int i = wave;
        float xs[4], trs[4], bl[4];
        float mx = -1e30f;
#pragma unroll
        for (int c = 0; c < 4; ++c) {
            int v = (c << 6) | lane;
            bl[c] = lds_bb[v];
            float tr = lds_tot[v] - lds_pwT[(i << 8) + (v ^ (i << 2))];
            trs[c] = tr;
            float x = (tr + bl[c]) * temp;
            xs[c] = x; mx = fmaxf(mx, x);
        }
        mx = fmaxf(wredmax(mx), 0.f);
        float se = 0.f, s1 = 0.f, s2 = 0.f;
#pragma unroll
        for (int c = 0; c < 4; ++c) {
            float e = __expf(xs[c] - mx);
            se += e; s1 += e * trs[c]; s2 += e * bl[c];
        }
        se = wredsum(se) + __expf(-mx);
        s1 = wredsum(s1);
        s2 = wredsum(s2);
        if (lane == 0) { lds_rcs[i] = s1 / se; lds_rb[i] = s2 / se; }
    }
    __syncthreads();   // b2: ch ready

    // chosen welfare per agent (wave i -> agent i); pwT still valid
    {
        const int i = wave;
        float cwv = 0.f;
#pragma unroll
        for (int c = 0; c < 4; ++c) {
            int v = (c << 6) | lane;
            cwv += lds_ch[v] * lds_pwT[(i << 8) + (v ^ (i << 2))];
        }
        cwv = wredsum(cwv);
        if (lane == 0) lds_cw[i] = cwv;
    }
    // item allocation from registers: each wave reduces its 32 s-rows
    {
        const float ch0 = lds_ch[sg], ch1 = lds_ch[64 + sg],
                    ch2 = lds_ch[128 + sg], ch3 = lds_ch[192 + sg];
        float vs[16];
#pragma unroll
        for (int wd = 0; wd < 16; ++wd) {
            float t = Pf[0][wd]*ch0 + Pf[1][wd]*ch1 + Pf[2][wd]*ch2 + Pf[3][wd]*ch3;
            t += __shfl_xor(t, 8);
            t += __shfl_xor(t, 16);
            t += __shfl_xor(t, 32);
            vs[wd] = t;   // lanes 0..7 now carry the n=0..7 slices for this wave
        }
        if (lane < 8) {
            float4* d4 = (float4*)(lds_scr + (wave << 7) + (lane << 4));
            d4[0] = make_float4(vs[0],  vs[1],  vs[2],  vs[3]);
            d4[1] = make_float4(vs[4],  vs[5],  vs[6],  vs[7]);
            d4[2] = make_float4(vs[8],  vs[9],  vs[10], vs[11]);
            d4[3] = make_float4(vs[12], vs[13], vs[14], vs[15]);
        }
    }
    __syncthreads();   // b3: scratch + cw ready. LAST barrier — all stores below.

    // ---- epilogue: every global store happens after the final barrier ----
#pragma unroll
    for (int c = 0; c < 4; ++c) {
        const int s = (c << 6) + sg;
        float4* dst = (float4*)(out_all + (bb * SFULL + s) * NM) + (n << 2);
        dst[0] = make_float4(Pf[c][0],  Pf[c][1],  Pf[c][2],  Pf[c][3]);
        dst[1] = make_float4(Pf[c][4],  Pf[c][5],  Pf[c][6],  Pf[c][7]);
        dst[2] = make_float4(Pf[c][8],  Pf[c][9],  Pf[c][10], Pf[c][11]);
        dst[3] = make_float4(Pf[c][12], Pf[c][13], Pf[c][14], Pf[c][15]);
    }
    if (u < 32) {
        ((float4*)(out_all + (bb * SFULL + MENU) * NM))[u] =
            make_float4(0.f, 0.f, 0.f, 0.f);
    }
    if (u < SFULL) out_choice[bb * SFULL + u] = lds_ch[u];
    if (u < NM) {
        float sum = 0.f;
#pragma unroll
        for (int w = 0; w < 8; ++w) sum += lds_scr[(w << 7) + u];
        out_item[bb * NM + u] = sum;
    }
    if (u < NAGENTS) {
        float ctot = 0.f;
#pragma unroll
        for (int k = 0; k < NAGENTS; ++k) ctot += lds_cw[k];
        float pay = (lds_rcs[u] + lds_rb[u] - (ctot - lds_cw[u]) - lds_ab)
                    / wvec[bb * NAGENTS + u];
        out_pay[(size_t)u * Bsz + b] = pay;
    }
}

extern "C" void kernel_launch(void* const* d_in, const int* in_sizes, int n_in,
                              void* d_out, int out_size, void* d_ws, size_t ws_size,
                              hipStream_t stream) {
    const float* bids   = (const float*)d_in[0];
    const float* allocs = (const float*)d_in[1];
    const float* wvec   = (const float*)d_in[2];
    const float* bvec   = (const float*)d_in[3];
    const float* tempp  = (const float*)d_in[4];
    float* out = (float*)d_out;
    const int Bsz = in_sizes[0] / (NAGENTS * MITEMS);  // 4096
    cama_kernel<<<Bsz, 512, 0, stream>>>(bids, allocs, wvec, bvec, tempp, out, Bsz);
}

// Round 4
// 267.861 us; speedup vs baseline: 1.0128x; 1.0128x over previous
//
#include <hip/hip_runtime.h>

#define NAGENTS 8
#define NM 128          // NAGENTS*MITEMS
#define MENU 256
#define SFULL 257       // MENU + null entry

// Raw barrier: wait LDS ops only (NO vmcnt drain — keeps prefetch loads and
// copy-out stores in flight across phases). "memory" clobber pins memory-op
// program order across the barrier.
#define BAR() asm volatile("s_waitcnt lgkmcnt(0)\n\ts_barrier" ::: "memory")

__device__ __forceinline__ float wredmax(float v) {
#pragma unroll
    for (int o = 32; o; o >>= 1) v = fmaxf(v, __shfl_xor(v, o));
    return v;
}
__device__ __forceinline__ float wredsum(float v) {
#pragma unroll
    for (int o = 32; o; o >>= 1) v += __shfl_xor(v, o);
    return v;
}

// Persistent: 256 blocks x 1024 threads, 1 block/CU (LDS ~144KB), each block
// processes `iters` consecutive auctions. Next auction's payload is loaded
// into registers right after the current payload's last use, and completes
// under the softmax/item phases (barriers never drain vmcnt).
__global__ __launch_bounds__(1024, 4) void cama_kernel(
    const float* __restrict__ bids,   // B,8,16
    const float* __restrict__ allocs, // B,256,8,16
    const float* __restrict__ wvec,   // B,8
    const float* __restrict__ bvec,   // B,256
    const float* __restrict__ tempp,  // 1
    float* __restrict__ out, int Bsz, int iters)
{
    __shared__ float4 lda4[MENU * 32];            // 128KB swizzled payload
    __shared__ float lds_pwT[NAGENTS * MENU];     // 8KB, [n][s^(n<<2)]
    __shared__ float lds_tot[MENU];
    __shared__ float lds_bb[2][MENU];             // double-buffered b
    __shared__ __align__(16) float lds_bids[2][NM];
    __shared__ float lds_w[2][NAGENTS];
    __shared__ float lds_ch[SFULL];
    __shared__ float lds_rcs[NAGENTS], lds_rb[NAGENTS], lds_cw[NAGENTS];
    __shared__ float lds_ab;

    const int u = threadIdx.x;       // 0..1023
    const int lane = u & 63;
    const int wave = u >> 6;         // 0..15
    const int n = u & 7;             // agent slice owned by this thread
    const int sg = u >> 3;           // 0..127

    float* out_choice = out;                                  // B*257
    float* out_item   = out + (size_t)Bsz * SFULL;            // B*128
    float* out_pay    = out_item + (size_t)Bsz * NM;          // 8*B
    float* out_all    = out_pay + (size_t)NAGENTS * Bsz;      // B*257*128

    const float temp = tempp[0];

    size_t a = (size_t)blockIdx.x * iters;   // first auction for this block

    float Pf[2][16];   // payload rows s = sg and s = 128+sg (agent-n slice)

    // ---- prologue: smalls + payload for first auction ----
    {
        float rbb = 0.f, rbid = 0.f, rw = 0.f;
        if (u < MENU)    rbb  = bvec[a * MENU + u];
        if (u < NM)      rbid = bids[a * NM + u];
        if (u < NAGENTS) rw   = wvec[a * NAGENTS + u];
        const float4* s0 = (const float4*)(allocs + (a * MENU + sg) * NM) + (n << 2);
        const float4* s1 = (const float4*)(allocs + (a * MENU + 128 + sg) * NM) + (n << 2);
        float4 a0 = s0[0], a1 = s0[1], a2 = s0[2], a3 = s0[3];
        float4 b0 = s1[0], b1 = s1[1], b2 = s1[2], b3 = s1[3];
        Pf[0][0]=a0.x;  Pf[0][1]=a0.y;  Pf[0][2]=a0.z;  Pf[0][3]=a0.w;
        Pf[0][4]=a1.x;  Pf[0][5]=a1.y;  Pf[0][6]=a1.z;  Pf[0][7]=a1.w;
        Pf[0][8]=a2.x;  Pf[0][9]=a2.y;  Pf[0][10]=a2.z; Pf[0][11]=a2.w;
        Pf[0][12]=a3.x; Pf[0][13]=a3.y; Pf[0][14]=a3.z; Pf[0][15]=a3.w;
        Pf[1][0]=b0.x;  Pf[1][1]=b0.y;  Pf[1][2]=b0.z;  Pf[1][3]=b0.w;
        Pf[1][4]=b1.x;  Pf[1][5]=b1.y;  Pf[1][6]=b1.z;  Pf[1][7]=b1.w;
        Pf[1][8]=b2.x;  Pf[1][9]=b2.y;  Pf[1][10]=b2.z; Pf[1][11]=b2.w;
        Pf[1][12]=b3.x; Pf[1][13]=b3.y; Pf[1][14]=b3.z; Pf[1][15]=b3.w;
        if (u < MENU)    lds_bb[0][u]   = rbb;
        if (u < NM)      lds_bids[0][u] = rbid;
        if (u < NAGENTS) lds_w[0][u]    = rw;
    }
    BAR();

    for (int it = 0; it < iters; ++it) {
        const int p = it & 1;

        // ---- welfare phase: read Pf, copy-out store, LDS payload + pw ----
        float qf[16];
        {
            const float4* bq = (const float4*)(&lds_bids[p][0]) + (n << 2);
            float4 qa = bq[0], qb = bq[1], qc = bq[2], qd = bq[3];
            qf[0]=qa.x; qf[1]=qa.y; qf[2]=qa.z; qf[3]=qa.w;
            qf[4]=qb.x; qf[5]=qb.y; qf[6]=qb.z; qf[7]=qb.w;
            qf[8]=qc.x; qf[9]=qc.y; qf[10]=qc.z; qf[11]=qc.w;
            qf[12]=qd.x; qf[13]=qd.y; qf[14]=qd.z; qf[15]=qd.w;
        }
        const float w_n = lds_w[p][n];
#pragma unroll
        for (int c = 0; c < 2; ++c) {
            const int s = (c << 7) + sg;
            float4 v0 = make_float4(Pf[c][0],  Pf[c][1],  Pf[c][2],  Pf[c][3]);
            float4 v1 = make_float4(Pf[c][4],  Pf[c][5],  Pf[c][6],  Pf[c][7]);
            float4 v2 = make_float4(Pf[c][8],  Pf[c][9],  Pf[c][10], Pf[c][11]);
            float4 v3 = make_float4(Pf[c][12], Pf[c][13], Pf[c][14], Pf[c][15]);
            float4* dst = (float4*)(out_all + (a * SFULL + s) * NM) + (n << 2);
            dst[0] = v0; dst[1] = v1; dst[2] = v2; dst[3] = v3;
            float util = 0.f;
#pragma unroll
            for (int k = 0; k < 16; ++k) util += Pf[c][k] * qf[k];
            float pwv = w_n * util;
            lds_pwT[(n << 8) + (s ^ (n << 2))] = pwv;
            float t4 = pwv;
            t4 += __shfl_xor(t4, 1);
            t4 += __shfl_xor(t4, 2);
            t4 += __shfl_xor(t4, 4);
            if (n == 0) lds_tot[s] = t4;
            const int base = s << 5, c7 = s & 7, j0 = n << 2;
            lda4[base + ((j0 + 0) ^ c7)] = v0;
            lda4[base + ((j0 + 1) ^ c7)] = v1;
            lda4[base + ((j0 + 2) ^ c7)] = v2;
            lda4[base + ((j0 + 3) ^ c7)] = v3;
        }
        if (u < 32)
            ((float4*)(out_all + (a * SFULL + MENU) * NM))[u] =
                make_float4(0.f, 0.f, 0.f, 0.f);

        // ---- prefetch next auction (loads fly across the barriers below) ----
        const bool has_next = (it + 1 < iters);
        const size_t an = a + 1;
        float rbb2 = 0.f, rbid2 = 0.f, rw2 = 0.f;
        if (has_next) {
            if (u < MENU)    rbb2  = bvec[an * MENU + u];
            if (u < NM)      rbid2 = bids[an * NM + u];
            if (u < NAGENTS) rw2   = wvec[an * NAGENTS + u];
            const float4* s0 = (const float4*)(allocs + (an * MENU + sg) * NM) + (n << 2);
            const float4* s1 = (const float4*)(allocs + (an * MENU + 128 + sg) * NM) + (n << 2);
            float4 a0 = s0[0], a1 = s0[1], a2 = s0[2], a3 = s0[3];
            float4 b0 = s1[0], b1 = s1[1], b2 = s1[2], b3 = s1[3];
            Pf[0][0]=a0.x;  Pf[0][1]=a0.y;  Pf[0][2]=a0.z;  Pf[0][3]=a0.w;
            Pf[0][4]=a1.x;  Pf[0][5]=a1.y;  Pf[0][6]=a1.z;  Pf[0][7]=a1.w;
            Pf[0][8]=a2.x;  Pf[0][9]=a2.y;  Pf[0][10]=a2.z; Pf[0][11]=a2.w;
            Pf[0][12]=a3.x; Pf[0][13]=a3.y; Pf[0][14]=a3.z; Pf[0][15]=a3.w;
            Pf[1][0]=b0.x;  Pf[1][1]=b0.y;  Pf[1][2]=b0.z;  Pf[1][3]=b0.w;
            Pf[1][4]=b1.x;  Pf[1][5]=b1.y;  Pf[1][6]=b1.z;  Pf[1][7]=b1.w;
            Pf[1][8]=b2.x;  Pf[1][9]=b2.y;  Pf[1][10]=b2.z; Pf[1][11]=b2.w;
            Pf[1][12]=b3.x; Pf[1][13]=b3.y; Pf[1][14]=b3.z; Pf[1][15]=b3.w;
        }
        BAR();   // b1: pwT/tot ready

        // ---- Round A: full softmax (wave 0) + 8 LOO softmaxes (waves 1..8) ----
        if (wave == 0) {
            float xs[4], bl[4], es[4];
            float mx = -1e30f;
#pragma unroll
            for (int c = 0; c < 4; ++c) {
                int v = (c << 6) | lane;
                bl[c] = lds_bb[p][v];
                float x = (lds_tot[v] + bl[c]) * temp;
                xs[c] = x; mx = fmaxf(mx, x);
            }
            mx = fmaxf(wredmax(mx), 0.f);   // null entry has x=0
            float se = 0.f, sab = 0.f;
#pragma unroll
            for (int c = 0; c < 4; ++c) { es[c] = __expf(xs[c] - mx); se += es[c]; sab += es[c] * bl[c]; }
            float en = __expf(-mx);
            se = wredsum(se) + en;
            sab = wredsum(sab);
            float inv = 1.f / se;
#pragma unroll
            for (int c = 0; c < 4; ++c) {
                int v = (c << 6) | lane;
                float chv = es[c] * inv;
                lds_ch[v] = chv;
                out_choice[a * SFULL + v] = chv;
            }
            if (lane == 0) {
                float chn = en * inv;
                lds_ch[MENU] = chn;
                out_choice[a * SFULL + MENU] = chn;
                lds_ab = sab * inv;
            }
        } else if (wave <= 8) {
            const int i = wave - 1;
            float xs[4], trs[4], bl[4];
            float mx = -1e30f;
#pragma unroll
            for (int c = 0; c < 4; ++c) {
                int v = (c << 6) | lane;
                bl[c] = lds_bb[p][v];
                float tr = lds_tot[v] - lds_pwT[(i << 8) + (v ^ (i << 2))];
                trs[c] = tr;
                float x = (tr + bl[c]) * temp;
                xs[c] = x; mx = fmaxf(mx, x);
            }
            mx = fmaxf(wredmax(mx), 0.f);
            float se = 0.f, s1 = 0.f, s2 = 0.f;
#pragma unroll
            for (int c = 0; c < 4; ++c) {
                float e = __expf(xs[c] - mx);
                se += e; s1 += e * trs[c]; s2 += e * bl[c];
            }
            se = wredsum(se) + __expf(-mx);
            s1 = wredsum(s1);
            s2 = wredsum(s2);
            if (lane == 0) { lds_rcs[i] = s1 / se; lds_rb[i] = s2 / se; }
        }
        BAR();   // b2: ch/rcs/rb/ab ready

        // ---- chosen welfare per agent (waves 0..7) ----
        if (wave < 8) {
            const int i = wave;
            float cwv = 0.f;
#pragma unroll
            for (int c = 0; c < 4; ++c) {
                int v = (c << 6) | lane;
                cwv += lds_ch[v] * lds_pwT[(i << 8) + (v ^ (i << 2))];
            }
            cwv = wredsum(cwv);
            if (lane == 0) lds_cw[i] = cwv;
        }
        // ---- item allocation (all 16 waves), direct store ----
        {
            const float* ldf = (const float*)lda4;
            const int wl = lane & 7, chunk = lane >> 3;
            const int nm = (wave << 3) + wl;
            const int jj = nm >> 2, r = nm & 3;
            float acc = 0.f;
#pragma unroll 8
            for (int it2 = 0; it2 < 32; ++it2) {
                int s = (it2 << 3) + chunk;
                acc += lds_ch[s] * ldf[(((s << 5) + (jj ^ (s & 7))) << 2) + r];
            }
            acc += __shfl_xor(acc, 8);
            acc += __shfl_xor(acc, 16);
            acc += __shfl_xor(acc, 32);
            if (chunk == 0) out_item[a * NM + nm] = acc;
        }
        // ---- stage next smalls (loads from prefetch are long complete) ----
        if (has_next) {
            if (u < MENU)    lds_bb[p ^ 1][u]   = rbb2;
            if (u < NM)      lds_bids[p ^ 1][u] = rbid2;
            if (u < NAGENTS) lds_w[p ^ 1][u]    = rw2;
        }
        BAR();   // b3: cw ready; payload/pwT safe to overwrite next iter

        // ---- payments ----
        if (u < NAGENTS) {
            float ctot = 0.f;
#pragma unroll
            for (int k = 0; k < NAGENTS; ++k) ctot += lds_cw[k];
            float pay = (lds_rcs[u] + lds_rb[u] - (ctot - lds_cw[u]) - lds_ab)
                        / lds_w[p][u];
            out_pay[(size_t)u * Bsz + a] = pay;
        }
        a = an;
    }
}

extern "C" void kernel_launch(void* const* d_in, const int* in_sizes, int n_in,
                              void* d_out, int out_size, void* d_ws, size_t ws_size,
                              hipStream_t stream) {
    const float* bids   = (const float*)d_in[0];
    const float* allocs = (const float*)d_in[1];
    const float* wvec   = (const float*)d_in[2];
    const float* bvec   = (const float*)d_in[3];
    const float* tempp  = (const float*)d_in[4];
    float* out = (float*)d_out;
    const int Bsz = in_sizes[0] / NM;          // 4096
    const int nblocks = 256;                   // 1 per CU
    const int iters = Bsz / nblocks;           // 16 (Bsz divisible by 256)
    cama_kernel<<<nblocks, 1024, 0, stream>>>(bids, allocs, wvec, bvec, tempp,
                                              out, Bsz, iters);
}

// Round 5
// 242.563 us; speedup vs baseline: 1.1184x; 1.1043x over previous
//
#include <hip/hip_runtime.h>

#define NAGENTS 8
#define NM 128          // NAGENTS*MITEMS
#define MENU 256
#define SFULL 257       // MENU + null entry

// Raw barrier: wait LDS ops only (NO vmcnt drain — keeps payload loads and
// copy-out stores in flight across phases).
#define BAR() asm volatile("s_waitcnt lgkmcnt(0)\n\ts_barrier" ::: "memory")

__device__ __forceinline__ float wredmax(float v) {
#pragma unroll
    for (int o = 32; o; o >>= 1) v = fmaxf(v, __shfl_xor(v, o));
    return v;
}
__device__ __forceinline__ float wredsum(float v) {
#pragma unroll
    for (int o = 32; o; o >>= 1) v += __shfl_xor(v, o);
    return v;
}

// Persistent: 256 blocks x 1024 threads, 1 block/CU. All payload traffic is
// lane-contiguous (float4 idx = k*1024 + u). Thread u owns agent n=(u>>2)&7,
// item-quad mq=u&3, rows s = 32k + (u>>5). Store regs (Sf) are decoupled from
// load regs (Pf) so no vmcnt hazard serializes stores against prefetch loads.
__global__ __launch_bounds__(1024, 4) void cama_kernel(
    const float* __restrict__ bids,   // B,8,16
    const float* __restrict__ allocs, // B,256,8,16
    const float* __restrict__ wvec,   // B,8
    const float* __restrict__ bvec,   // B,256
    const float* __restrict__ tempp,  // 1
    float* __restrict__ out, int Bsz, int iters)
{
    __shared__ float lds_pwT[NAGENTS * MENU];     // 8KB, [n][s^(n<<2)]
    __shared__ float lds_tot[MENU];
    __shared__ float lds_bb[2][MENU];             // double-buffered smalls
    __shared__ __align__(16) float lds_bids[2][NM];
    __shared__ float lds_w[2][NAGENTS];
    __shared__ float lds_ch[SFULL];
    __shared__ __align__(16) float lds_scr[16 * NM];  // 8KB item scratch
    __shared__ float lds_rcs[NAGENTS], lds_rb[NAGENTS], lds_cw[NAGENTS];
    __shared__ float lds_ab;

    const int u = threadIdx.x;       // 0..1023
    const int lane = u & 63;
    const int wave = u >> 6;         // 0..15
    const int n  = (u >> 2) & 7;     // agent owned by this thread
    const int mq = u & 3;            // item-quad owned
    const int su = u >> 5;           // row-within-32-block, 0..31

    float* out_choice = out;                                  // B*257
    float* out_item   = out + (size_t)Bsz * SFULL;            // B*128
    float* out_pay    = out_item + (size_t)Bsz * NM;          // 8*B
    float* out_all    = out_pay + (size_t)NAGENTS * Bsz;      // B*257*128
    float4* out_all4  = (float4*)out_all;
    const float4* all4 = (const float4*)allocs;

    const float temp = tempp[0];
    size_t a = (size_t)blockIdx.x * iters;

    float4 Pf[8];   // prefetched payload (next/current auction)

    // ---- prologue: payload + smalls for first auction ----
    {
        float rbb = 0.f, rbid = 0.f, rw = 0.f;
        if (u < MENU)    rbb  = bvec[a * MENU + u];
        if (u < NM)      rbid = bids[a * NM + u];
        if (u < NAGENTS) rw   = wvec[a * NAGENTS + u];
#pragma unroll
        for (int k = 0; k < 8; ++k)
            Pf[k] = all4[a * 8192 + (k << 10) + u];
        if (u < MENU)    lds_bb[0][u]   = rbb;
        if (u < NM)      lds_bids[0][u] = rbid;
        if (u < NAGENTS) lds_w[0][u]    = rw;
    }
    BAR();

    for (int it = 0; it < iters; ++it) {
        const int p = it & 1;
        const bool has_next = (it + 1 < iters);
        const size_t an = a + 1;

        // snapshot current payload; Pf is then free for the next prefetch
        float4 Sf[8];
#pragma unroll
        for (int k = 0; k < 8; ++k) Sf[k] = Pf[k];

        // prefetch next auction (in flight across the whole iteration)
        float rbb2 = 0.f, rbid2 = 0.f, rw2 = 0.f;
        if (has_next) {
#pragma unroll
            for (int k = 0; k < 8; ++k)
                Pf[k] = all4[an * 8192 + (k << 10) + u];
            if (u < MENU)    rbb2  = bvec[an * MENU + u];
            if (u < NM)      rbid2 = bids[an * NM + u];
            if (u < NAGENTS) rw2   = wvec[an * NAGENTS + u];
        }

        // copy-out (contiguous 1KB per wave-instruction)
#pragma unroll
        for (int k = 0; k < 8; ++k)
            out_all4[a * 8224 + (k << 10) + u] = Sf[k];
        if (u < 32)
            out_all4[a * 8224 + 8192 + u] = make_float4(0.f, 0.f, 0.f, 0.f);

        // ---- welfare from Sf ----
        const float4 q4 = ((const float4*)&lds_bids[p][0])[u & 31]; // q[n][mq*4..+3]
        const float w_n = lds_w[p][n];
#pragma unroll
        for (int k = 0; k < 8; ++k) {
            const int s = (k << 5) + su;
            float util = Sf[k].x*q4.x + Sf[k].y*q4.y + Sf[k].z*q4.z + Sf[k].w*q4.w;
            util += __shfl_xor(util, 1);
            util += __shfl_xor(util, 2);     // full item-dot for (s,n)
            float pwv = w_n * util;
            if (mq == 0) lds_pwT[(n << 8) + (s ^ (n << 2))] = pwv;
            float t = pwv;
            t += __shfl_xor(t, 4);
            t += __shfl_xor(t, 8);
            t += __shfl_xor(t, 16);          // sum over agents
            if ((lane & 31) == 0) lds_tot[s] = t;
        }
        BAR();   // b1: pwT/tot ready

        // ---- Round A: full softmax (wave 0) + 8 LOO softmaxes (waves 1..8) ----
        if (wave == 0) {
            float xs[4], bl[4], es[4];
            float mx = -1e30f;
#pragma unroll
            for (int c = 0; c < 4; ++c) {
                int v = (c << 6) | lane;
                bl[c] = lds_bb[p][v];
                float x = (lds_tot[v] + bl[c]) * temp;
                xs[c] = x; mx = fmaxf(mx, x);
            }
            mx = fmaxf(wredmax(mx), 0.f);   // null entry has x=0
            float se = 0.f, sab = 0.f;
#pragma unroll
            for (int c = 0; c < 4; ++c) { es[c] = __expf(xs[c] - mx); se += es[c]; sab += es[c] * bl[c]; }
            float en = __expf(-mx);
            se = wredsum(se) + en;
            sab = wredsum(sab);
            float inv = 1.f / se;
#pragma unroll
            for (int c = 0; c < 4; ++c) {
                int v = (c << 6) | lane;
                float chv = es[c] * inv;
                lds_ch[v] = chv;
                out_choice[a * SFULL + v] = chv;
            }
            if (lane == 0) {
                float chn = en * inv;
                lds_ch[MENU] = chn;
                out_choice[a * SFULL + MENU] = chn;
                lds_ab = sab * inv;
            }
        } else if (wave <= 8) {
            const int i = wave - 1;
            float xs[4], trs[4], bl[4];
            float mx = -1e30f;
#pragma unroll
            for (int c = 0; c < 4; ++c) {
                int v = (c << 6) | lane;
                bl[c] = lds_bb[p][v];
                float tr = lds_tot[v] - lds_pwT[(i << 8) + (v ^ (i << 2))];
                trs[c] = tr;
                float x = (tr + bl[c]) * temp;
                xs[c] = x; mx = fmaxf(mx, x);
            }
            mx = fmaxf(wredmax(mx), 0.f);
            float se = 0.f, s1 = 0.f, s2 = 0.f;
#pragma unroll
            for (int c = 0; c < 4; ++c) {
                float e = __expf(xs[c] - mx);
                se += e; s1 += e * trs[c]; s2 += e * bl[c];
            }
            se = wredsum(se) + __expf(-mx);
            s1 = wredsum(s1);
            s2 = wredsum(s2);
            if (lane == 0) { lds_rcs[i] = s1 / se; lds_rb[i] = s2 / se; }
        }
        BAR();   // b2: ch/rcs/rb/ab ready

        // ---- chosen welfare per agent (waves 0..7) ----
        if (wave < 8) {
            const int i = wave;
            float cwv = 0.f;
#pragma unroll
            for (int c = 0; c < 4; ++c) {
                int v = (c << 6) | lane;
                cwv += lds_ch[v] * lds_pwT[(i << 8) + (v ^ (i << 2))];
            }
            cwv = wredsum(cwv);
            if (lane == 0) lds_cw[i] = cwv;
        }
        // ---- item allocation partials from Sf registers ----
        {
            float ax = 0.f, ay = 0.f, az = 0.f, aw = 0.f;
#pragma unroll
            for (int k = 0; k < 8; ++k) {
                float chv = lds_ch[(k << 5) + su];
                ax += Sf[k].x * chv; ay += Sf[k].y * chv;
                az += Sf[k].z * chv; aw += Sf[k].w * chv;
            }
            ax += __shfl_xor(ax, 32);
            ay += __shfl_xor(ay, 32);
            az += __shfl_xor(az, 32);
            aw += __shfl_xor(aw, 32);
            if (lane < 32)   // word index = n*16 + m within this wave's slice
                ((float4*)lds_scr)[(wave << 5) + lane] = make_float4(ax, ay, az, aw);
        }
        // ---- stage next smalls (their loads are long complete) ----
        if (has_next) {
            if (u < MENU)    lds_bb[p ^ 1][u]   = rbb2;
            if (u < NM)      lds_bids[p ^ 1][u] = rbid2;
            if (u < NAGENTS) lds_w[p ^ 1][u]    = rw2;
        }
        BAR();   // b3: scr/cw ready; pwT/tot/ch safe to overwrite next iter

        // ---- item final reduce + payments ----
        if (u < NM) {
            float s = 0.f;
#pragma unroll
            for (int w = 0; w < 16; ++w) s += lds_scr[(w << 7) + u];
            out_item[a * NM + u] = s;
        }
        if (u < NAGENTS) {
            float ctot = 0.f;
#pragma unroll
            for (int k = 0; k < NAGENTS; ++k) ctot += lds_cw[k];
            float pay = (lds_rcs[u] + lds_rb[u] - (ctot - lds_cw[u]) - lds_ab)
                        / lds_w[p][u];
            out_pay[(size_t)u * Bsz + a] = pay;
        }
        a = an;
    }
}

extern "C" void kernel_launch(void* const* d_in, const int* in_sizes, int n_in,
                              void* d_out, int out_size, void* d_ws, size_t ws_size,
                              hipStream_t stream) {
    const float* bids   = (const float*)d_in[0];
    const float* allocs = (const float*)d_in[1];
    const float* wvec   = (const float*)d_in[2];
    const float* bvec   = (const float*)d_in[3];
    const float* tempp  = (const float*)d_in[4];
    float* out = (float*)d_out;
    const int Bsz = in_sizes[0] / NM;          // 4096
    const int nblocks = 256;                   // 1 per CU
    const int iters = Bsz / nblocks;           // 16
    cama_kernel<<<nblocks, 1024, 0, stream>>>(bids, allocs, wvec, bvec, tempp,
                                              out, Bsz, iters);
}